// Round 8
// baseline (1315.559 us; speedup 1.0000x reference)
//
#include <hip/hip_runtime.h>

// Kuramoto phase dynamics + coherence softmax. B*S=1024 rows, V=50257, 10 steps.
// One 768-thread block per row. ALL phase state in registers:
//   p[66] planes (plane k: elem k*768+tid; plane 65 valid for tid<337 only)
//   w[32] = 0.1*omega for the first 32 planes; remaining planes re-load omega
//   from L2 each step (omega is 201KB, row-invariant -> L2-resident).
// __launch_bounds__(768,3): 12 waves/CU (3/SIMD), VGPR cap ~170; need ~150.
// No DS ops in the hot loop (LDS only holds the 2x32-float reduce buffer).
// Plain lagged sums (S,C from previous step's phases): validated r7,
// absmax 2.38e-7 vs 6.6e-7 threshold. One barrier/step (double-buffered red).
// Step 9 peeled: accumulates sum(p_final) instead of sin/cos sums.

#define V_DIM   50257
#define NROWS   1024
#define NT      768
#define NP      66
#define NFULL   65            // full planes; plane 65 has TAILN valid lanes
#define TAILN   337           // 50257 - 65*768
#define NW      32            // omega-cached planes
#define INV2PI  0.15915494309189535f

__device__ __forceinline__ float fsin(float r) { return __builtin_amdgcn_sinf(r); }
__device__ __forceinline__ float fcos(float r) { return __builtin_amdgcn_cosf(r); }

__device__ __forceinline__ void block_reduce2(float& a, float& b, float* red) {
    #pragma unroll
    for (int off = 32; off > 0; off >>= 1) {
        a += __shfl_xor(a, off, 64);
        b += __shfl_xor(b, off, 64);
    }
    const int wid = threadIdx.x >> 6;
    if ((threadIdx.x & 63) == 0) { red[wid] = a; red[16 + wid] = b; }
    __syncthreads();
    float ta = 0.f, tb = 0.f;
    #pragma unroll
    for (int i = 0; i < NT / 64; ++i) { ta += red[i]; tb += red[16 + i]; }
    a = ta; b = tb;
}

__global__ __launch_bounds__(NT, 3)
void kuramoto_kernel(const float* __restrict__ logits,
                     const float* __restrict__ omega,
                     const float* __restrict__ noise,
                     float* __restrict__ out) {
    __shared__ float red[2][32];

    const int tid = threadIdx.x;
    const size_t base = (size_t)blockIdx.x * V_DIM;
    const float* __restrict__ lg = logits + base;
    const float* __restrict__ nz = noise + base;
    float* __restrict__ op = out + base;

    const float dtc = 0.1f * (0.1f / (float)V_DIM);   // DT * coupling
    int rp = 0;

    // ---- init: p = noise + 0.1*logits; cache w; sums of sin/cos(p0) ----
    float p[NP], w[NW];
    float ss = 0.f, cc = 0.f;
    #pragma unroll
    for (int k = 0; k < NFULL; ++k) {
        const int idx = k * NT + tid;
        const float ph = nz[idx] + 0.1f * lg[idx];
        p[k] = ph;
        if (k < NW) w[k] = 0.1f * omega[idx];
        const float r = ph * INV2PI;
        ss += fsin(r); cc += fcos(r);
    }
    if (tid < TAILN) {
        const int idx = NFULL * NT + tid;
        const float ph = nz[idx] + 0.1f * lg[idx];
        p[NFULL] = ph;
        const float r = ph * INV2PI;
        ss += fsin(r); cc += fcos(r);
    }
    block_reduce2(ss, cc, red[rp]); rp ^= 1;
    float S = ss, C = cc;

    // ---- steps 0..8: update with lagged sums; accumulate new sums ----
    for (int st = 0; st < 9; ++st) {
        const float dC = dtc * C, dS = dtc * S;
        float nss = 0.f, ncc = 0.f;
        #pragma unroll
        for (int k = 0; k < NFULL; ++k) {
            const float r = p[k] * INV2PI;
            const float s = fsin(r), c = fcos(r);
            const float t = c * dS;
            const float u = __builtin_fmaf(s, dC, -t);   // s*dC - c*dS
            const float om = (k < NW) ? w[k] : 0.1f * omega[k * NT + tid];
            p[k] += om + u;
            nss += s; ncc += c;
        }
        if (tid < TAILN) {
            const float r = p[NFULL] * INV2PI;
            const float s = fsin(r), c = fcos(r);
            const float t = c * dS;
            const float u = __builtin_fmaf(s, dC, -t);
            p[NFULL] += 0.1f * omega[NFULL * NT + tid] + u;
            nss += s; ncc += c;
        }
        block_reduce2(nss, ncc, red[rp]); rp ^= 1;
        S = nss; C = ncc;
    }

    // ---- step 9 (peeled): update + accumulate sum(p_final) ----
    float psum = 0.f, d0 = 0.f;
    {
        const float dC = dtc * C, dS = dtc * S;
        #pragma unroll
        for (int k = 0; k < NFULL; ++k) {
            const float r = p[k] * INV2PI;
            const float s = fsin(r), c = fcos(r);
            const float t = c * dS;
            const float u = __builtin_fmaf(s, dC, -t);
            const float om = (k < NW) ? w[k] : 0.1f * omega[k * NT + tid];
            p[k] += om + u;
            psum += p[k];
        }
        if (tid < TAILN) {
            const float r = p[NFULL] * INV2PI;
            const float s = fsin(r), c = fcos(r);
            const float t = c * dS;
            const float u = __builtin_fmaf(s, dC, -t);
            p[NFULL] += 0.1f * omega[NFULL * NT + tid] + u;
            psum += p[NFULL];
        }
    }
    block_reduce2(psum, d0, red[rp]); rp ^= 1;
    const float mean = psum / (float)V_DIM;

    // ---- e = exp(cos(p - mean)) in place; reduce esum ----
    float esum = 0.f, d1 = 0.f;
    #pragma unroll
    for (int k = 0; k < NFULL; ++k) {
        const float e = __expf(fcos((p[k] - mean) * INV2PI));
        p[k] = e;
        esum += e;
    }
    if (tid < TAILN) {
        const float e = __expf(fcos((p[NFULL] - mean) * INV2PI));
        p[NFULL] = e;
        esum += e;
    }
    block_reduce2(esum, d1, red[rp]); rp ^= 1;
    const float inv = 1.f / esum;

    // ---- store ----
    #pragma unroll
    for (int k = 0; k < NFULL; ++k) {
        op[k * NT + tid] = p[k] * inv;
    }
    if (tid < TAILN) op[NFULL * NT + tid] = p[NFULL] * inv;
}

extern "C" void kernel_launch(void* const* d_in, const int* in_sizes, int n_in,
                              void* d_out, int out_size, void* d_ws, size_t ws_size,
                              hipStream_t stream) {
    const float* logits = (const float*)d_in[0];
    const float* omega  = (const float*)d_in[1];  // natural_frequencies [V]
    const float* noise  = (const float*)d_in[2];
    float* out = (float*)d_out;
    (void)d_ws; (void)ws_size; (void)in_sizes; (void)n_in; (void)out_size;

    kuramoto_kernel<<<NROWS, NT, 0, stream>>>(logits, omega, noise, out);
}

// Round 9
// 571.468 us; speedup vs baseline: 2.3021x; 2.3021x over previous
//
#include <hip/hip_runtime.h>

// Kuramoto phase dynamics + coherence softmax. B*S=1024 rows, V=50257, 10 steps.
// One 768-thread block per row, TWO blocks/CU (the round-9 lever):
//   - p[40] in registers (pair-mapped, float2 global I/O). Fully-unrolled reg
//     loops (partial unroll would make p[] runtime-indexed -> scratch), with
//     sched_barrier(0) every 5 pairs to bound scheduler live ranges (r5/r8
//     lesson: the allocator pins ~84 VGPR at 768t and spills past it).
//   - 24 elems/thread in LDS as 12 float2 pair-planes (73.7 KiB) + 2 tail
//     planes -> total LDS ~78.4 KiB <= 80 KiB -> 2 blocks/CU, 6 waves/SIMD
//     (r7 was 1 block/CU, 45% VALUBusy, latency-bound).
// Omega is NOT cached in regs: re-loaded from L2 each step (row-invariant,
// 201 KB, shared across all blocks -> L2-resident).
// Plain lagged sums (S,C from previous step), validated r7 (absmax 2.38e-7).
// One barrier per step via double-buffered red[2][32]. Step 9 peeled
// (accumulates sum(p_final), killing the separate mean pass).

#define V_DIM   50257
#define NROWS   1024
#define NT      768
#define NKK     20                      // register float2 pairs -> p[40]
#define NPAIR   12                      // LDS float2 pair-planes
#define PAIR_B  (NKK * 2 * NT)          // 30720
#define PT0_B   (PAIR_B + NPAIR * 2 * NT) // 49152
#define PT1_B   (PT0_B + NT)            // 49920
#define TAILN   (V_DIM - PT1_B)         // 337
#define INV2PI  0.15915494309189535f

__device__ __forceinline__ float fsin(float r) { return __builtin_amdgcn_sinf(r); }
__device__ __forceinline__ float fcos(float r) { return __builtin_amdgcn_cosf(r); }
#define SCHED_FENCE() __builtin_amdgcn_sched_barrier(0)

__device__ __forceinline__ void block_reduce2(float& a, float& b, float* red) {
    #pragma unroll
    for (int off = 32; off > 0; off >>= 1) {
        a += __shfl_xor(a, off, 64);
        b += __shfl_xor(b, off, 64);
    }
    const int wid = threadIdx.x >> 6;
    if ((threadIdx.x & 63) == 0) { red[wid] = a; red[16 + wid] = b; }
    __syncthreads();
    float ta = 0.f, tb = 0.f;
    #pragma unroll
    for (int i = 0; i < NT / 64; ++i) { ta += red[i]; tb += red[16 + i]; }
    a = ta; b = tb;
}

__global__ __launch_bounds__(NT, 3)
void kuramoto_kernel(const float* __restrict__ logits,
                     const float* __restrict__ omega,
                     const float* __restrict__ noise,
                     float* __restrict__ out) {
    __shared__ float2 pl2[NPAIR][NT];   // 73,728 B
    __shared__ float  pt0[NT];          // 3,072 B
    __shared__ float  pt1[TAILN];       // 1,348 B
    __shared__ float  red[2][32];       // 256 B

    const int tid = threadIdx.x;
    const size_t base = (size_t)blockIdx.x * V_DIM;
    const float* __restrict__ lg = logits + base;
    const float* __restrict__ nz = noise + base;
    float* __restrict__ op = out + base;

    const float dtc = 0.1f * (0.1f / (float)V_DIM);   // DT * coupling
    int rp = 0;

    // ---- init: p = noise + 0.1*logits; sums of sin/cos(p0) ----
    float p[2 * NKK];
    float ss = 0.f, cc = 0.f;
    #pragma unroll
    for (int kk = 0; kk < NKK; ++kk) {
        const int e = kk * (2 * NT) + 2 * tid;
        const float2 l2 = *(const float2*)(lg + e);
        const float2 n2 = *(const float2*)(nz + e);
        const float phx = n2.x + 0.1f * l2.x;
        const float phy = n2.y + 0.1f * l2.y;
        p[2 * kk] = phx; p[2 * kk + 1] = phy;
        ss += fsin(phx * INV2PI) + fsin(phy * INV2PI);
        cc += fcos(phx * INV2PI) + fcos(phy * INV2PI);
        if ((kk % 5) == 4) SCHED_FENCE();
    }
    #pragma unroll 4
    for (int j = 0; j < NPAIR; ++j) {
        const int e = PAIR_B + j * (2 * NT) + 2 * tid;
        const float2 l2 = *(const float2*)(lg + e);
        const float2 n2 = *(const float2*)(nz + e);
        const float phx = n2.x + 0.1f * l2.x;
        const float phy = n2.y + 0.1f * l2.y;
        pl2[j][tid] = make_float2(phx, phy);
        ss += fsin(phx * INV2PI) + fsin(phy * INV2PI);
        cc += fcos(phx * INV2PI) + fcos(phy * INV2PI);
    }
    {
        const float ph0 = nz[PT0_B + tid] + 0.1f * lg[PT0_B + tid];
        pt0[tid] = ph0;
        ss += fsin(ph0 * INV2PI); cc += fcos(ph0 * INV2PI);
        if (tid < TAILN) {
            const float ph1 = nz[PT1_B + tid] + 0.1f * lg[PT1_B + tid];
            pt1[tid] = ph1;
            ss += fsin(ph1 * INV2PI); cc += fcos(ph1 * INV2PI);
        }
    }
    block_reduce2(ss, cc, red[rp]); rp ^= 1;
    float S = ss, C = cc;

    // ---- steps 0..8: update with lagged sums; accumulate new sums ----
    for (int st = 0; st < 9; ++st) {
        const float dC = dtc * C, dS = dtc * S;
        float nss = 0.f, ncc = 0.f;
        #pragma unroll
        for (int kk = 0; kk < NKK; ++kk) {
            const int e = kk * (2 * NT) + 2 * tid;
            const float2 o2 = *(const float2*)(omega + e);
            const float rx = p[2 * kk] * INV2PI, ry = p[2 * kk + 1] * INV2PI;
            const float sx = fsin(rx), cx = fcos(rx);
            const float sy = fsin(ry), cy = fcos(ry);
            p[2 * kk]     += 0.1f * o2.x + (sx * dC - cx * dS);
            p[2 * kk + 1] += 0.1f * o2.y + (sy * dC - cy * dS);
            nss += sx + sy; ncc += cx + cy;
            if ((kk % 5) == 4) SCHED_FENCE();
        }
        #pragma unroll 4
        for (int j = 0; j < NPAIR; ++j) {
            float2 ph = pl2[j][tid];
            const int e = PAIR_B + j * (2 * NT) + 2 * tid;
            const float2 o2 = *(const float2*)(omega + e);
            const float rx = ph.x * INV2PI, ry = ph.y * INV2PI;
            const float sx = fsin(rx), cx = fcos(rx);
            const float sy = fsin(ry), cy = fcos(ry);
            ph.x += 0.1f * o2.x + (sx * dC - cx * dS);
            ph.y += 0.1f * o2.y + (sy * dC - cy * dS);
            pl2[j][tid] = ph;
            nss += sx + sy; ncc += cx + cy;
        }
        {
            float ph0 = pt0[tid];
            const float r0 = ph0 * INV2PI;
            const float s0 = fsin(r0), c0 = fcos(r0);
            pt0[tid] = ph0 + 0.1f * omega[PT0_B + tid] + (s0 * dC - c0 * dS);
            nss += s0; ncc += c0;
            if (tid < TAILN) {
                float ph1 = pt1[tid];
                const float r1 = ph1 * INV2PI;
                const float s1 = fsin(r1), c1 = fcos(r1);
                pt1[tid] = ph1 + 0.1f * omega[PT1_B + tid] + (s1 * dC - c1 * dS);
                nss += s1; ncc += c1;
            }
        }
        block_reduce2(nss, ncc, red[rp]); rp ^= 1;
        S = nss; C = ncc;
    }

    // ---- step 9 (peeled): update + accumulate sum(p_final) ----
    float psum = 0.f, d0 = 0.f;
    {
        const float dC = dtc * C, dS = dtc * S;
        #pragma unroll
        for (int kk = 0; kk < NKK; ++kk) {
            const int e = kk * (2 * NT) + 2 * tid;
            const float2 o2 = *(const float2*)(omega + e);
            const float rx = p[2 * kk] * INV2PI, ry = p[2 * kk + 1] * INV2PI;
            const float sx = fsin(rx), cx = fcos(rx);
            const float sy = fsin(ry), cy = fcos(ry);
            p[2 * kk]     += 0.1f * o2.x + (sx * dC - cx * dS);
            p[2 * kk + 1] += 0.1f * o2.y + (sy * dC - cy * dS);
            psum += p[2 * kk] + p[2 * kk + 1];
            if ((kk % 5) == 4) SCHED_FENCE();
        }
        #pragma unroll 4
        for (int j = 0; j < NPAIR; ++j) {
            float2 ph = pl2[j][tid];
            const int e = PAIR_B + j * (2 * NT) + 2 * tid;
            const float2 o2 = *(const float2*)(omega + e);
            const float rx = ph.x * INV2PI, ry = ph.y * INV2PI;
            ph.x += 0.1f * o2.x + (fsin(rx) * dC - fcos(rx) * dS);
            ph.y += 0.1f * o2.y + (fsin(ry) * dC - fcos(ry) * dS);
            pl2[j][tid] = ph;
            psum += ph.x + ph.y;
        }
        {
            float ph0 = pt0[tid];
            const float r0 = ph0 * INV2PI;
            ph0 += 0.1f * omega[PT0_B + tid] + (fsin(r0) * dC - fcos(r0) * dS);
            pt0[tid] = ph0;
            psum += ph0;
            if (tid < TAILN) {
                float ph1 = pt1[tid];
                const float r1 = ph1 * INV2PI;
                ph1 += 0.1f * omega[PT1_B + tid] + (fsin(r1) * dC - fcos(r1) * dS);
                pt1[tid] = ph1;
                psum += ph1;
            }
        }
    }
    block_reduce2(psum, d0, red[rp]); rp ^= 1;
    const float mean = psum / (float)V_DIM;

    // ---- e = exp(cos(p - mean)) in place; reduce esum ----
    float esum = 0.f, d1 = 0.f;
    #pragma unroll
    for (int kk = 0; kk < NKK; ++kk) {
        const float ex = __expf(fcos((p[2 * kk] - mean) * INV2PI));
        const float ey = __expf(fcos((p[2 * kk + 1] - mean) * INV2PI));
        p[2 * kk] = ex; p[2 * kk + 1] = ey;
        esum += ex + ey;
        if ((kk % 5) == 4) SCHED_FENCE();
    }
    #pragma unroll 4
    for (int j = 0; j < NPAIR; ++j) {
        float2 ph = pl2[j][tid];
        const float ex = __expf(fcos((ph.x - mean) * INV2PI));
        const float ey = __expf(fcos((ph.y - mean) * INV2PI));
        pl2[j][tid] = make_float2(ex, ey);
        esum += ex + ey;
    }
    {
        const float e0 = __expf(fcos((pt0[tid] - mean) * INV2PI));
        pt0[tid] = e0;
        esum += e0;
        if (tid < TAILN) {
            const float e1 = __expf(fcos((pt1[tid] - mean) * INV2PI));
            pt1[tid] = e1;
            esum += e1;
        }
    }
    block_reduce2(esum, d1, red[rp]); rp ^= 1;
    const float inv = 1.f / esum;

    // ---- stores (dwordx2 on paired regions) ----
    #pragma unroll
    for (int kk = 0; kk < NKK; ++kk) {
        const int e = kk * (2 * NT) + 2 * tid;
        *(float2*)(op + e) = make_float2(p[2 * kk] * inv, p[2 * kk + 1] * inv);
        if ((kk % 5) == 4) SCHED_FENCE();
    }
    #pragma unroll 4
    for (int j = 0; j < NPAIR; ++j) {
        const int e = PAIR_B + j * (2 * NT) + 2 * tid;
        const float2 ph = pl2[j][tid];
        *(float2*)(op + e) = make_float2(ph.x * inv, ph.y * inv);
    }
    op[PT0_B + tid] = pt0[tid] * inv;
    if (tid < TAILN) op[PT1_B + tid] = pt1[tid] * inv;
}

extern "C" void kernel_launch(void* const* d_in, const int* in_sizes, int n_in,
                              void* d_out, int out_size, void* d_ws, size_t ws_size,
                              hipStream_t stream) {
    const float* logits = (const float*)d_in[0];
    const float* omega  = (const float*)d_in[1];  // natural_frequencies [V]
    const float* noise  = (const float*)d_in[2];
    float* out = (float*)d_out;
    (void)d_ws; (void)ws_size; (void)in_sizes; (void)n_in; (void)out_size;

    kuramoto_kernel<<<NROWS, NT, 0, stream>>>(logits, omega, noise, out);
}